// Round 13
// baseline (211.391 us; speedup 1.0000x reference)
//
#include <hip/hip_runtime.h>
#include <hip/hip_bf16.h>

#define BIGF 1e30f
#define TC 80   // channels
#define TN 512  // sequence length (N == M)
#define L2E 1.4426950408889634f   // log2(e)
#define LN2 0.6931471805599453f   // 1/log2(e)

typedef float f32x2 __attribute__((ext_vector_type(2)));
typedef float f32x4 __attribute__((ext_vector_type(4)));
typedef short s16x8 __attribute__((ext_vector_type(8)));
typedef __attribute__((address_space(1))) const unsigned int gu32;
typedef __attribute__((address_space(3))) unsigned int lu32;

// ---------------------------------------------------------------------------
// Kernel 1: pairwise squared distances via BF16 MFMA, skewed store, log2e.
// BYTE-IDENTICAL to the verified round-12 kernel (absmax 0.0).
// ---------------------------------------------------------------------------
__global__ __launch_bounds__(256) void pairdist_kernel(
    const float* __restrict__ x, const float* __restrict__ y,
    float* __restrict__ F) {
  const int b  = blockIdx.z;
  const int n0 = blockIdx.x * 128;  // jj tile (A / M dim)
  const int m0 = blockIdx.y * 128;  // i tile  (B / N dim)

  __shared__ __align__(16) short Ab[128 * 128];  // bf16, 256B row stride
  __shared__ __align__(16) short Bb[128 * 128];
  __shared__ float xxs[128], yys[128];

  const float* xb = x + (size_t)b * TC * TN;
  const float* yb = y + (size_t)b * TC * TN;
  const int tid = threadIdx.x;

  auto sw = [](int row, int k) -> int {
    return (row * 256 + k * 2) ^ ((row & 7) << 4);
  };
  auto cvt = [](float f) -> unsigned short {   // RNE f32 -> bf16
    unsigned u = __float_as_uint(f);
    return (unsigned short)((u + 0x7FFFu + ((u >> 16) & 1u)) >> 16);
  };

  // Stage 12 k-octets (c=0..79 data, 80..95 exact zeros) x 128 rows x 2.
  for (int item = tid; item < 12 * 128 * 2; item += 256) {
    int arr = (item >= 12 * 128) ? 1 : 0;
    int it  = item - arr * 12 * 128;
    int oct = it >> 7, n = it & 127;
    const float* src = arr ? (yb + m0 + n) : (xb + n0 + n);
    s16x8 pk;
#pragma unroll
    for (int j = 0; j < 8; ++j) {
      int c = oct * 8 + j;
      float v = (c < TC) ? src[(size_t)c * TN] : 0.f;
      pk[j] = (short)cvt(v);
    }
    short* dst = arr ? Bb : Ab;
    *(s16x8*)((char*)dst + sw(n, oct * 8)) = pk;
  }

  // Norms fp32-exact from global (coalesced per c across the half-block).
  if (tid < 128) {
    float s = 0.f;
    for (int c = 0; c < TC; ++c) {
      float v = xb[(size_t)c * TN + n0 + tid];
      s += v * v;
    }
    xxs[tid] = s;
  } else {
    int n = tid - 128;
    float s = 0.f;
    for (int c = 0; c < TC; ++c) {
      float v = yb[(size_t)c * TN + m0 + n];
      s += v * v;
    }
    yys[n] = s;
  }
  __syncthreads();

  // MFMA main: wave (wm, wn) computes 64x64.
  const int l  = tid & 63;
  const int w  = tid >> 6;
  const int wm = (w >> 1) * 64, wn = (w & 1) * 64;
  const int fr = l & 15;          // A-row / B-col index
  const int fk = (l >> 4) * 8;    // k base within K-step

  f32x4 acc[4][4] = {};
#pragma unroll
  for (int ks = 0; ks < 3; ++ks) {
    const int k0 = ks * 32 + fk;
    s16x8 af[4], bfr[4];
#pragma unroll
    for (int ta = 0; ta < 4; ++ta)
      af[ta] = *(const s16x8*)((const char*)Ab + sw(wm + ta * 16 + fr, k0));
#pragma unroll
    for (int tq = 0; tq < 4; ++tq)
      bfr[tq] = *(const s16x8*)((const char*)Bb + sw(wn + tq * 16 + fr, k0));
#pragma unroll
    for (int ta = 0; ta < 4; ++ta)
#pragma unroll
      for (int tq = 0; tq < 4; ++tq)
        acc[ta][tq] = __builtin_amdgcn_mfma_f32_16x16x32_bf16(
            af[ta], bfr[tq], acc[ta][tq], 0, 0, 0);
  }

  // Epilogue: D-layout col=lane&15, row=(lane>>4)*4+reg; skewed scalar
  // stores, identical mapping/expression to the verified round-11 kernel.
  float* Fb = F + (size_t)b * TN * TN;
#pragma unroll
  for (int ta = 0; ta < 4; ++ta) {
    const int mb = wm + ta * 16 + (l >> 4) * 4;
#pragma unroll
    for (int r = 0; r < 4; ++r) {
      const int jj = n0 + mb + r;
      const float xxv = xxs[mb + r];
#pragma unroll
      for (int tq = 0; tq < 4; ++tq) {
        const int nn = wn + tq * 16 + fr;
        const int i  = m0 + nn;
        float val = (xxv + yys[nn] - 2.f * acc[ta][tq][r]) * L2E;
        int p = (jj + (i >> 1)) & (TN - 1);
        Fb[(size_t)p * TN + i] = val;
      }
    }
  }
}

// ---------------------------------------------------------------------------
// Kernel 2: soft-DTW, TWO BATCHES PER BLOCK (16 blocks x 512 threads).
//
// Round-12 diagnosis: 32 blocks x 4 waves = 1 wave/SIMD -> the softmin
// chain's latency is fully exposed (287 cy/iter vs ~80 cy of issue). Fix:
// waves 0-3 run batch 2*bx, waves 4-7 run batch 2*bx+1 on the SAME 4 SIMDs
// -> 2 independent waves/SIMD interleave and hide each other's latency.
// Per-batch machinery is UNCHANGED from the verified round-10/12 kernel
// (skew j = s - 71w - g + 1, 8-slot LDS ring, block-batched parity-buffered
// mailbox, raw s_barrier per 8-iter block, bit-identical cell math).
// The shared barrier bounds skew for both batches jointly (same cadence).
// Indexing widened: w = (tid>>6)&3 (wave within batch), bt = tid>>8 (batch
// half), ring[8][..] by LDS wave slot tid>>6, hand[2][..] by batch,
// up_p=0 at tid 0 and 256, outputs at tid 255 / 511.
// ---------------------------------------------------------------------------
__global__ __launch_bounds__(512) __attribute__((amdgpu_waves_per_eu(2)))
void sdtw_kernel(const float* __restrict__ Ft, float* __restrict__ out) {
  const int tid = threadIdx.x;
  const int g   = tid & 63;         // lane
  const int wv  = tid >> 6;         // LDS wave slot 0..7
  const int w   = wv & 3;           // wave within batch
  const int bt  = tid >> 8;         // batch half 0/1
  const int b   = blockIdx.x * 2 + bt;
  const float* Fb = Ft + (size_t)b * TN * TN;

  __shared__ float ring[8][8][128];       // per-wave 8 slots x 512 B
  __shared__ f32x4 hand[2][3][2][2];      // [batch][boundary][parity][2]

  // Init mailboxes to BIG (pre-start consumers read the boundary value).
  if (tid < 24) {
    f32x4 iv; iv[0] = BIGF; iv[1] = BIGF; iv[2] = BIGF; iv[3] = BIGF;
    ((f32x4*)hand)[tid] = iv;
  }
  __syncthreads();                  // one-time; before any DMA is in flight

  float p0 = BIGF, p1 = BIGF;       // left values of my 2 rows
  float up_p = ((tid & 255) == 0) ? 0.f : BIGF;  // R[0][0]=0 per batch

  // Stage iteration u for this wave: row (u-7w)&511, cols 128w..128w+127.
  auto stage = [&](int slot, int u) {
    const float* gp =
        Fb + (size_t)((u - 7 * w) & (TN - 1)) * TN + w * 128 + g;
    __builtin_amdgcn_global_load_lds((gu32*)gp,        (lu32*)&ring[wv][slot][0],  4, 0, 0);
    __builtin_amdgcn_global_load_lds((gu32*)(gp + 64), (lu32*)&ring[wv][slot][64], 4, 0, 0);
  };

  const unsigned rbase =
      (unsigned)(size_t)(__attribute__((address_space(3))) float*)&ring[wv][0][0];
  const unsigned hbase =
      (unsigned)(size_t)(__attribute__((address_space(3))) f32x4*)&hand[bt][0][0][0];

  // One DP cell, bit-identical to rounds 7-12.
  auto cell = [&](float d, float r0, float r1, float r2) -> float {
    float mn, md, mx;
    asm("v_min3_f32 %0, %3, %4, %5\n\t"
        "v_med3_f32 %1, %3, %4, %5\n\t"
        "v_max3_f32 %2, %3, %4, %5"
        : "=&v"(mn), "=&v"(md), "=&v"(mx)
        : "v"(r0), "v"(r1), "v"(r2));
    float e1 = __builtin_amdgcn_exp2f(mn - md);
    float e2 = __builtin_amdgcn_exp2f(mn - mx);
    float dm = d + mn;
    float ss = (1.0f + e1) + e2;
    return dm - __builtin_amdgcn_logf(ss);
  };

  // Body: pubk = producer bottom from iter s-8 (wave-uniform broadcast;
  // BIG for wave 0 of each batch). Lane g's up value comes from lane g-1
  // (1-iter delay) via DPP wave_shr:1; lane 0 takes pubk.
  auto body = [&](f32x2 d, float pubk) -> float {
    float upc = __int_as_float(__builtin_amdgcn_update_dpp(
        __float_as_int(pubk), __float_as_int(p1), 0x138, 0xf, 0xf, false));
    float c0 = cell(d[0], up_p, upc, p0);   // top row
    float c1 = cell(d[1], p0, c0, p1);      // bottom row
    p0 = c0; p1 = c1; up_p = upc;
    return c1;
  };

  // Preamble: stage slots 0..7 (iters 0..7) -> 16 outstanding DMA per wave.
  stage(0, 0); stage(1, 1); stage(2, 2); stage(3, 3);
  stage(4, 4); stage(5, 5); stage(6, 6); stage(7, 7);

  f32x2 d0, d1, d2, d3, d4, d5, d6, d7;

  // Main: 98 blocks x 8 bodies (iters 0..783).
  int s = 0;
  for (int B = 0; B < 98; ++B, s += 8) {
    __builtin_amdgcn_s_barrier();   // raw: orders publish(B-1) before read
    asm volatile("s_waitcnt vmcnt(0)" ::: "memory");  // staged 1 block ago

    unsigned ad = rbase + (unsigned)(g * 8);          // my float2 per slot
    asm volatile(
        "ds_read_b64 %0, %8\n\t"
        "ds_read_b64 %1, %8 offset:512\n\t"
        "ds_read_b64 %2, %8 offset:1024\n\t"
        "ds_read_b64 %3, %8 offset:1536\n\t"
        "ds_read_b64 %4, %8 offset:2048\n\t"
        "ds_read_b64 %5, %8 offset:2560\n\t"
        "ds_read_b64 %6, %8 offset:3072\n\t"
        "ds_read_b64 %7, %8 offset:3584\n\t"
        "s_waitcnt lgkmcnt(0)"
        : "=&v"(d0), "=&v"(d1), "=&v"(d2), "=&v"(d3),
          "=&v"(d4), "=&v"(d5), "=&v"(d6), "=&v"(d7)
        : "v"(ad)
        : "memory");

    // Previous block's 8 producer bottoms (parity (B-1)&1 == (B+1)&1).
    f32x4 pA, pB;
    if (w > 0) {
      unsigned ha = hbase + (unsigned)(((w - 1) * 2 + ((B + 1) & 1)) * 32);
      asm volatile("ds_read_b128 %0, %2\n\t"
                   "ds_read_b128 %1, %2 offset:16\n\t"
                   "s_waitcnt lgkmcnt(0)"
                   : "=&v"(pA), "=&v"(pB) : "v"(ha) : "memory");
    } else {
      pA[0] = pA[1] = pA[2] = pA[3] = BIGF;
      pB[0] = pB[1] = pB[2] = pB[3] = BIGF;
    }

    // Refill all 8 slots for the NEXT block (ds_reads above are complete).
    stage(0, s + 8);  stage(1, s + 9);
    stage(2, s + 10); stage(3, s + 11);
    stage(4, s + 12); stage(5, s + 13);
    stage(6, s + 14); stage(7, s + 15);

    f32x4 k0, k1;
    k0[0] = body(d0, pA[0]); k0[1] = body(d1, pA[1]);
    k0[2] = body(d2, pA[2]); k0[3] = body(d3, pA[3]);
    k1[0] = body(d4, pB[0]); k1[1] = body(d5, pB[1]);
    k1[2] = body(d6, pB[2]); k1[3] = body(d7, pB[3]);

    // Publish this block's 8 bottoms for the next wave (parity B&1).
    if (w < 3 && g == 63) {
      unsigned wa = hbase + (unsigned)((w * 2 + (B & 1)) * 32);
      asm volatile("ds_write_b128 %0, %1\n\t"
                   "ds_write_b128 %0, %2 offset:16\n\t"
                   "s_waitcnt lgkmcnt(0)"
                   :: "v"(wa), "v"(k0), "v"(k1) : "memory");
    }
  }

  // Tail: iters 784..787 (4 bodies, slots 0..3, staged during block 97).
  __builtin_amdgcn_s_barrier();
  asm volatile("s_waitcnt vmcnt(0)" ::: "memory");
  {
    unsigned ad = rbase + (unsigned)(g * 8);
    asm volatile(
        "ds_read_b64 %0, %4\n\t"
        "ds_read_b64 %1, %4 offset:512\n\t"
        "ds_read_b64 %2, %4 offset:1024\n\t"
        "ds_read_b64 %3, %4 offset:1536\n\t"
        "s_waitcnt lgkmcnt(0)"
        : "=&v"(d0), "=&v"(d1), "=&v"(d2), "=&v"(d3)
        : "v"(ad)
        : "memory");
  }
  f32x4 pA;
  if (w > 0) {
    // Producer block-97 values, parity 97&1 = 1; need positions 0..3.
    unsigned ha = hbase + (unsigned)(((w - 1) * 2 + 1) * 32);
    asm volatile("ds_read_b128 %0, %1\n\ts_waitcnt lgkmcnt(0)"
                 : "=&v"(pA) : "v"(ha) : "memory");
  } else {
    pA[0] = pA[1] = pA[2] = pA[3] = BIGF;
  }
  body(d0, pA[0]); body(d1, pA[1]); body(d2, pA[2]); body(d3, pA[3]);

  // R[512][512] = pipeline 255 of each batch (its wave 3, lane 63).
  if (w == 3 && g == 63) out[b] = p1 * LN2;
}

extern "C" void kernel_launch(void* const* d_in, const int* in_sizes, int n_in,
                              void* d_out, int out_size, void* d_ws, size_t ws_size,
                              hipStream_t stream) {
  const float* x = (const float*)d_in[0];
  const float* y = (const float*)d_in[1];
  float* out = (float*)d_out;
  float* F = (float*)d_ws;  // 32*512*512*4 = 33.5 MB, skewed layout

  dim3 g1(TN / 128, TN / 128, 32);
  // Swapped args -> values are D^T (up to bf16 rounding), skewed + scaled.
  pairdist_kernel<<<g1, 256, 0, stream>>>(y, x, F);
  sdtw_kernel<<<16, 512, 0, stream>>>(F, out);
}